// Round 4
// baseline (482.698 us; speedup 1.0000x reference)
//
#include <hip/hip_runtime.h>

// GAT layer: N=8192, IN_DIM=128, OUT_DIM=64, alpha=0.2
// out = elu( softmax_row( mask(lrelu(s1_i + s2_j), adj) ) @ Wh )
//
// R4: split the fused adj-streamer (stuck at ~185us across R2/R3 despite
// occupancy + coalescing fixes) into two observable, structurally simple
// kernels:
//   p_kernel: pure stream adj(int32)->P(fp16) row-major, 384 MB traffic,
//             memcpy-shaped (floor ~61us). No LDS, no MFMA, tiny VGPR.
//   gemm:     P @ Wh_t (M=8192,N=64,K=8192) fp16 MFMA, K-split x8,
//             register-direct fragments (R2-verified layouts), ones-column
//             row sums; P is L3-resident (just written).

#define N 8192
#define IN_DIM 128
#define OUT_DIM 64
#define ALPHA 0.2f
#define LOG2E 1.44269504088896f
#define KC 8  // K-chunks in gemm

typedef _Float16 half8 __attribute__((ext_vector_type(8)));
typedef _Float16 half4 __attribute__((ext_vector_type(4)));
typedef float f32x4 __attribute__((ext_vector_type(4)));

// ---------------------------------------------------------------------------
// Kernel 1: Wh = x@W (fp16, transposed [f][i]); s1L = log2e*Wh·a1; s2L likewise
// ---------------------------------------------------------------------------
__global__ __launch_bounds__(64) void wh_kernel(
    const float* __restrict__ x, const float* __restrict__ W,
    const float* __restrict__ a, _Float16* __restrict__ Wh_t,
    float* __restrict__ s1L, float* __restrict__ s2L) {
  __shared__ float xs[IN_DIM];
  const int i = blockIdx.x;
  const int t = threadIdx.x;  // 0..63 = output feature f

  xs[t]      = x[(size_t)i * IN_DIM + t];
  xs[t + 64] = x[(size_t)i * IN_DIM + 64 + t];
  __syncthreads();

  float wh = 0.f;
#pragma unroll
  for (int d = 0; d < IN_DIM; ++d) wh = fmaf(xs[d], W[d * OUT_DIM + t], wh);

  Wh_t[(size_t)t * N + i] = (_Float16)wh;

  float p1 = wh * a[t];
  float p2 = wh * a[64 + t];
#pragma unroll
  for (int off = 32; off; off >>= 1) {
    p1 += __shfl_down(p1, off);
    p2 += __shfl_down(p2, off);
  }
  if (t == 0) {
    s1L[i] = p1 * LOG2E;
    s2L[i] = p2 * LOG2E;
  }
}

// ---------------------------------------------------------------------------
// Kernel 2: ML = lrelu(max(s1L)+max(s2L)) (scaled domain; log2e>0 so max and
// lrelu commute with the scaling). Global upper bound -> exp2(score-ML)<=1,
// fp16-safe, softmax ratios identical, j-associative.
// ---------------------------------------------------------------------------
__global__ __launch_bounds__(256) void max_kernel(
    const float* __restrict__ s1L, const float* __restrict__ s2L,
    float* __restrict__ Mout) {
  __shared__ float red[8];
  const int t = threadIdx.x;
  float m1 = -1e30f, m2 = -1e30f;
  for (int idx = t; idx < N; idx += 256) {
    m1 = fmaxf(m1, s1L[idx]);
    m2 = fmaxf(m2, s2L[idx]);
  }
#pragma unroll
  for (int off = 32; off; off >>= 1) {
    m1 = fmaxf(m1, __shfl_down(m1, off));
    m2 = fmaxf(m2, __shfl_down(m2, off));
  }
  if ((t & 63) == 0) {
    red[t >> 6] = m1;
    red[4 + (t >> 6)] = m2;
  }
  __syncthreads();
  if (t == 0) {
    m1 = fmaxf(fmaxf(red[0], red[1]), fmaxf(red[2], red[3]));
    m2 = fmaxf(fmaxf(red[4], red[5]), fmaxf(red[6], red[7]));
    float e = m1 + m2;
    Mout[0] = fmaxf(e, ALPHA * e);
  }
}

// ---------------------------------------------------------------------------
// Kernel 3: pure stream. 8 elements/thread: P[i][j] = adj ? exp2(lrelu(sL)-ML)
// : 0, fp16 row-major. Per wave: 2 KB contiguous adj read, 1 KB contiguous P
// write. 32768 blocks.
// ---------------------------------------------------------------------------
__global__ __launch_bounds__(256) void p_kernel(
    const int* __restrict__ adj, const float* __restrict__ s1L,
    const float* __restrict__ s2L, const float* __restrict__ Mptr,
    _Float16* __restrict__ P) {
  const size_t e0 = ((size_t)blockIdx.x * 256 + threadIdx.x) * 8;
  const int i = (int)(e0 >> 13);    // row (N = 2^13)
  const int j = (int)(e0 & 8191);   // col of first element
  const float ML = Mptr[0];
  const float s1v = s1L[i];

  const int4 a0 = *(const int4*)(adj + e0);
  const int4 a1 = *(const int4*)(adj + e0 + 4);
  const float4 sa = *(const float4*)(s2L + j);
  const float4 sb = *(const float4*)(s2L + j + 4);

  const int av[8] = {a0.x, a0.y, a0.z, a0.w, a1.x, a1.y, a1.z, a1.w};
  const float sv[8] = {sa.x, sa.y, sa.z, sa.w, sb.x, sb.y, sb.z, sb.w};
  half8 hv;
#pragma unroll
  for (int c = 0; c < 8; ++c) {
    const float tt = s1v + sv[c];
    const float uu = fmaxf(tt, ALPHA * tt);
    const float pv = exp2f(uu - ML);
    hv[c] = (_Float16)(av[c] != 0 ? pv : 0.f);
  }
  *(half8*)(P + e0) = hv;
}

// ---------------------------------------------------------------------------
// Kernel 4: C = P @ Wh_t^T-ish: M=8192, N=64(+1 ones col), K=8192.
// grid (M/64, KC); wave w owns rows i0..i0+15, K-chunk of 1024 (32 steps).
// Register-direct fragments (verified in R2):
//   A[m=r16][k=q*8+e]  <- P[(i0+r16)*N + k0 + q*8]      (16B/lane)
//   B[k=q*8+e][n=r16]  <- Wh_t[(fg*16+r16)*N + k0+q*8]  (L2-resident)
//   ones column in B -> acc[4] = row sums of fp16 P (exact normalizer)
// No LDS, no barriers.
// ---------------------------------------------------------------------------
__global__ __launch_bounds__(256, 4) void gemm_kernel(
    const _Float16* __restrict__ P, const _Float16* __restrict__ Wh_t,
    float* __restrict__ accp, float* __restrict__ lp) {
  const int t = threadIdx.x;
  const int w = t >> 6;
  const int lane = t & 63;
  const int q = lane >> 4;
  const int r16 = lane & 15;
  const int i0 = blockIdx.x * 64 + w * 16;
  const int c = blockIdx.y;
  const int kb = c * (N / KC);

  half8 bones;
#pragma unroll
  for (int e = 0; e < 8; ++e)
    bones[e] = (r16 == 0) ? (_Float16)1.0f : (_Float16)0.0f;

  f32x4 acc[5] = {{0.f, 0.f, 0.f, 0.f}, {0.f, 0.f, 0.f, 0.f},
                  {0.f, 0.f, 0.f, 0.f}, {0.f, 0.f, 0.f, 0.f},
                  {0.f, 0.f, 0.f, 0.f}};

  const _Float16* pA = P + (size_t)(i0 + r16) * N + kb + q * 8;
  const _Float16* pB = Wh_t + (size_t)r16 * N + kb + q * 8;

#pragma unroll 4
  for (int ks = 0; ks < (N / KC) / 32; ++ks) {
    const half8 aF = *(const half8*)(pA + ks * 32);
#pragma unroll
    for (int fg = 0; fg < 4; ++fg) {
      const half8 bf = *(const half8*)(pB + (size_t)fg * 16 * N + ks * 32);
      acc[fg] =
          __builtin_amdgcn_mfma_f32_16x16x32_f16(aF, bf, acc[fg], 0, 0, 0);
    }
    acc[4] =
        __builtin_amdgcn_mfma_f32_16x16x32_f16(aF, bones, acc[4], 0, 0, 0);
  }

  // C/D layout: row = q*4+r, col = r16 (per 16-col fg block)
#pragma unroll
  for (int fg = 0; fg < 4; ++fg) {
#pragma unroll
    for (int r = 0; r < 4; ++r) {
      accp[((size_t)c * N + i0 + q * 4 + r) * OUT_DIM + fg * 16 + r16] =
          acc[fg][r];
    }
  }
  if (r16 == 0) {
#pragma unroll
    for (int r = 0; r < 4; ++r) lp[(size_t)c * N + i0 + q * 4 + r] = acc[4][r];
  }
}

// ---------------------------------------------------------------------------
// Kernel 5: combine KC partials, normalize, ELU.
// ---------------------------------------------------------------------------
__global__ __launch_bounds__(256) void reduce_kernel(
    const float* __restrict__ accp, const float* __restrict__ lp,
    float* __restrict__ out) {
  const int tid = blockIdx.x * 256 + threadIdx.x;  // over N*OUT_DIM
  const int i = tid >> 6;                          // row
  float s = 0.f, l = 0.f;
#pragma unroll
  for (int c = 0; c < KC; ++c) s += accp[(size_t)c * N * OUT_DIM + tid];
#pragma unroll
  for (int c = 0; c < KC; ++c) l += lp[(size_t)c * N + i];
  float v = s / l;
  out[tid] = v > 0.f ? v : expm1f(v);
}

// ---------------------------------------------------------------------------
extern "C" void kernel_launch(void* const* d_in, const int* in_sizes, int n_in,
                              void* d_out, int out_size, void* d_ws,
                              size_t ws_size, hipStream_t stream) {
  const float* x = (const float*)d_in[0];
  const int* adj = (const int*)d_in[1];
  const float* W = (const float*)d_in[2];
  const float* a = (const float*)d_in[3];
  float* out = (float*)d_out;

  char* ws = (char*)d_ws;
  _Float16* Wh_t = (_Float16*)ws;               // 1 MiB
  float* s1L = (float*)(ws + (1u << 20));       // 32 KiB
  float* s2L = s1L + N;                         // 32 KiB
  float* M = s2L + N;                           // 4 B
  _Float16* P = (_Float16*)(ws + (2u << 20));   // N*N*2 = 128 MiB
  float* accp = (float*)(ws + (132u << 20));    // KC*N*64*4 = 16 MiB
  float* lp = accp + (size_t)KC * N * OUT_DIM;  // 256 KiB

  wh_kernel<<<N, 64, 0, stream>>>(x, W, a, Wh_t, s1L, s2L);
  max_kernel<<<1, 256, 0, stream>>>(s1L, s2L, M);
  p_kernel<<<(int)((size_t)N * N / 8 / 256), 256, 0, stream>>>(adj, s1L, s2L,
                                                               M, P);
  gemm_kernel<<<dim3(N / 64, KC), 256, 0, stream>>>(P, Wh_t, accp, lp);
  reduce_kernel<<<N * OUT_DIM / 256, 256, 0, stream>>>(accp, lp, out);
}

// Round 5
// 407.020 us; speedup vs baseline: 1.1859x; 1.1859x over previous
//
#include <hip/hip_runtime.h>

// GAT layer: N=8192, IN_DIM=128, OUT_DIM=64, alpha=0.2
// out = elu( softmax_row( mask(lrelu(s1_i + s2_j), adj) ) @ Wh )
//
// R5: fused single-pass attn with ZERO scattered global loads.
// Theory: R2/R4's stall was TA serialization of scattered b128 loads (every
// lane a distinct 128-B line: A-frags from P rows, B-frags from Wh_t rows).
//  - adj: lane-contiguous (2 rows x 512 B per instr), register prefetch d=1
//  - B-frags: pre-packed by bpack_kernel into Bpack[kt][fg][lane] so the hot
//    loop's B loads are base+lane*16 contiguous 1-KB, L2-resident (1 MB)
//  - A-frags: via per-wave LDS buffer (no barriers, pad LDP=136)
//  - reverse row order: harvest adj-restore L3 residency (tail rows hot)
//  - ones-column B -> row sums from the matrix pipe (exact normalizer)

#define N 8192
#define IN_DIM 128
#define OUT_DIM 64
#define ALPHA 0.2f
#define LOG2E 1.44269504088896f
#define JC 8             // j-chunks
#define CW (N / JC)      // 1024 cols per chunk
#define TW 128           // cols per tile
#define NT (CW / TW)     // 8 tiles
#define LDP 136          // LDS row stride (halfs)

typedef _Float16 half8 __attribute__((ext_vector_type(8)));
typedef _Float16 half4 __attribute__((ext_vector_type(4)));
typedef float f32x4 __attribute__((ext_vector_type(4)));

// ---------------------------------------------------------------------------
// Kernel 1: Wh = x@W (fp16, transposed [f][i]); s1L/s2L = log2e * scores
// ---------------------------------------------------------------------------
__global__ __launch_bounds__(64) void wh_kernel(
    const float* __restrict__ x, const float* __restrict__ W,
    const float* __restrict__ a, _Float16* __restrict__ Wh_t,
    float* __restrict__ s1L, float* __restrict__ s2L) {
  __shared__ float xs[IN_DIM];
  const int i = blockIdx.x;
  const int t = threadIdx.x;  // 0..63 = output feature f

  xs[t]      = x[(size_t)i * IN_DIM + t];
  xs[t + 64] = x[(size_t)i * IN_DIM + 64 + t];
  __syncthreads();

  float wh = 0.f;
#pragma unroll
  for (int d = 0; d < IN_DIM; ++d) wh = fmaf(xs[d], W[d * OUT_DIM + t], wh);

  Wh_t[(size_t)t * N + i] = (_Float16)wh;

  float p1 = wh * a[t];
  float p2 = wh * a[64 + t];
#pragma unroll
  for (int off = 32; off; off >>= 1) {
    p1 += __shfl_down(p1, off);
    p2 += __shfl_down(p2, off);
  }
  if (t == 0) {
    s1L[i] = p1 * LOG2E;
    s2L[i] = p2 * LOG2E;
  }
}

// ---------------------------------------------------------------------------
// Kernel 2: c0 = exp2(-ML), ML = lrelu(max(s1L)+max(s2L)) (scaled domain).
// Global bound -> p = exp2(uu)*c0 <= 1: fp16-safe, ratios exact,
// j-associative. exp2(uu) <= exp2(ML) ~ 600, no f32 overflow.
// ---------------------------------------------------------------------------
__global__ __launch_bounds__(256) void max_kernel(
    const float* __restrict__ s1L, const float* __restrict__ s2L,
    float* __restrict__ c0out) {
  __shared__ float red[8];
  const int t = threadIdx.x;
  float m1 = -1e30f, m2 = -1e30f;
  for (int idx = t; idx < N; idx += 256) {
    m1 = fmaxf(m1, s1L[idx]);
    m2 = fmaxf(m2, s2L[idx]);
  }
#pragma unroll
  for (int off = 32; off; off >>= 1) {
    m1 = fmaxf(m1, __shfl_down(m1, off));
    m2 = fmaxf(m2, __shfl_down(m2, off));
  }
  if ((t & 63) == 0) {
    red[t >> 6] = m1;
    red[4 + (t >> 6)] = m2;
  }
  __syncthreads();
  if (t == 0) {
    m1 = fmaxf(fmaxf(red[0], red[1]), fmaxf(red[2], red[3]));
    m2 = fmaxf(fmaxf(red[4], red[5]), fmaxf(red[6], red[7]));
    float e = m1 + m2;
    c0out[0] = exp2f(-fmaxf(e, ALPHA * e));
  }
}

// ---------------------------------------------------------------------------
// Kernel 3: pack B-fragments. Bpack[((kt*4+fg)*64+lane)*8 ..] = the half8
// lane needs for (k-step kt, feature-group fg): Wh_t[fg*16+r16][kt*32+q*8..+7]
// One-time scattered 1-MB gather -> contiguous layout for the hot loop.
// ---------------------------------------------------------------------------
__global__ __launch_bounds__(256) void bpack_kernel(
    const _Float16* __restrict__ Wh_t, _Float16* __restrict__ Bpack) {
  const int kt = blockIdx.x;  // 0..255 (32-wide k steps)
  const int t = threadIdx.x;
  const int fg = t >> 6;
  const int lane = t & 63;
  const int q = (t >> 4) & 3;
  const int r16 = t & 15;
  const half8 v =
      *(const half8*)(Wh_t + (size_t)(fg * 16 + r16) * N + kt * 32 + q * 8);
  *(half8*)(Bpack + ((size_t)(kt * 4 + fg) * 64 + lane) * 8) = v;
}

// ---------------------------------------------------------------------------
// Kernel 4: fused adj streamer. grid (N/64, JC), 4 waves; wave w: rows
// i0..i0+15, cols [c*1024,+1024) in 8 tiles of 128. All global loads
// lane-contiguous. Per-wave LDS for the A-frag layout change; no barriers.
// ---------------------------------------------------------------------------
__global__ __launch_bounds__(256, 4) void attn_kernel(
    const int* __restrict__ adj, const _Float16* __restrict__ Bpack,
    const float* __restrict__ s1L, const float* __restrict__ s2L,
    const float* __restrict__ c0p, float* __restrict__ accp,
    float* __restrict__ lp) {
  __shared__ __align__(16) _Float16 Ps[4 * 16 * LDP];

  const int t = threadIdx.x;
  const int w = t >> 6;
  const int lane = t & 63;
  const int q = lane >> 4;
  const int r16 = lane & 15;
  const int half_ = lane >> 5;  // which row of the 2-row load pair
  const int l32 = lane & 31;    // position in the 512-B row segment
  const int rb = (int)(gridDim.x - 1 - blockIdx.x);  // reverse: tail rows hot
  const int i0 = rb * 64 + w * 16;
  const int c = blockIdx.y;
  const int jb = c * CW;

  const float c0 = c0p[0];

  float s1v8[8];
#pragma unroll
  for (int it = 0; it < 8; ++it) s1v8[it] = s1L[i0 + 2 * it + half_];

  half8 bones;
#pragma unroll
  for (int e = 0; e < 8; ++e)
    bones[e] = (r16 == 0) ? (_Float16)1.0f : (_Float16)0.0f;

  f32x4 acc[5] = {{0.f, 0.f, 0.f, 0.f}, {0.f, 0.f, 0.f, 0.f},
                  {0.f, 0.f, 0.f, 0.f}, {0.f, 0.f, 0.f, 0.f},
                  {0.f, 0.f, 0.f, 0.f}};

  const int* aprow = adj + (size_t)(i0 + half_) * N + jb + l32 * 4;
  _Float16* Pw = Ps + w * 16 * LDP;
  const _Float16* ldA = Pw + r16 * LDP + q * 8;
  _Float16* stP = Pw + half_ * LDP + l32 * 4;

  // preload tile 0
  int4 av[8];
#pragma unroll
  for (int it = 0; it < 8; ++it)
    av[it] = *(const int4*)(aprow + (size_t)(2 * it) * N);

  for (int jt = 0; jt < NT; ++jt) {
    const int j0 = jb + jt * TW;
    const int joff_next = ((jt + 1) & (NT - 1)) * TW;  // wrap: harmless reload

    // prefetch next tile's adj (independent, stays in flight through compute)
    int4 nv[8];
#pragma unroll
    for (int it = 0; it < 8; ++it)
      nv[it] = *(const int4*)(aprow + joff_next + (size_t)(2 * it) * N);

    const float4 sv = *(const float4*)(s2L + j0 + l32 * 4);

    // P tile -> per-wave LDS (fp16). 7 VALU/elem: add,mul,max,exp2,mul,sel,cvt
#pragma unroll
    for (int it = 0; it < 8; ++it) {
      const float s1v = s1v8[it];
      float tt, uu;
      half4 hv;
      tt = s1v + sv.x; uu = fmaxf(tt, ALPHA * tt);
      hv[0] = (_Float16)(av[it].x != 0 ? exp2f(uu) * c0 : 0.f);
      tt = s1v + sv.y; uu = fmaxf(tt, ALPHA * tt);
      hv[1] = (_Float16)(av[it].y != 0 ? exp2f(uu) * c0 : 0.f);
      tt = s1v + sv.z; uu = fmaxf(tt, ALPHA * tt);
      hv[2] = (_Float16)(av[it].z != 0 ? exp2f(uu) * c0 : 0.f);
      tt = s1v + sv.w; uu = fmaxf(tt, ALPHA * tt);
      hv[3] = (_Float16)(av[it].w != 0 ? exp2f(uu) * c0 : 0.f);
      *(half4*)(stP + (2 * it) * LDP) = hv;
    }

    // MFMA: A from LDS (same-wave order guarantees no hazard), B from Bpack
    const int ktb = c * 32 + jt * 4;  // global 32-k-step index base
#pragma unroll
    for (int ks = 0; ks < 4; ++ks) {
      const half8 aF = *(const half8*)(ldA + ks * 32);
      const _Float16* bp = Bpack + ((size_t)(ktb + ks) * 4 * 64 + lane) * 8;
#pragma unroll
      for (int fg = 0; fg < 4; ++fg) {
        const half8 bf = *(const half8*)(bp + (size_t)fg * 64 * 8);
        acc[fg] =
            __builtin_amdgcn_mfma_f32_16x16x32_f16(aF, bf, acc[fg], 0, 0, 0);
      }
      acc[4] =
          __builtin_amdgcn_mfma_f32_16x16x32_f16(aF, bones, acc[4], 0, 0, 0);
    }

#pragma unroll
    for (int it = 0; it < 8; ++it) av[it] = nv[it];
  }

  // store partials. C/D: row = q*4+r, col = r16 (per fg block)
#pragma unroll
  for (int fg = 0; fg < 4; ++fg) {
#pragma unroll
    for (int r = 0; r < 4; ++r) {
      accp[((size_t)c * N + i0 + q * 4 + r) * OUT_DIM + fg * 16 + r16] =
          acc[fg][r];
    }
  }
  if (r16 == 0) {
#pragma unroll
    for (int r = 0; r < 4; ++r) lp[(size_t)c * N + i0 + q * 4 + r] = acc[4][r];
  }
}

// ---------------------------------------------------------------------------
// Kernel 5: combine JC partials, normalize, ELU.
// ---------------------------------------------------------------------------
__global__ __launch_bounds__(256) void reduce_kernel(
    const float* __restrict__ accp, const float* __restrict__ lp,
    float* __restrict__ out) {
  const int tid = blockIdx.x * 256 + threadIdx.x;  // over N*OUT_DIM
  const int i = tid >> 6;                          // row
  float s = 0.f, l = 0.f;
#pragma unroll
  for (int c = 0; c < JC; ++c) s += accp[(size_t)c * N * OUT_DIM + tid];
#pragma unroll
  for (int c = 0; c < JC; ++c) l += lp[(size_t)c * N + i];
  float v = s / l;
  out[tid] = v > 0.f ? v : expm1f(v);
}

// ---------------------------------------------------------------------------
extern "C" void kernel_launch(void* const* d_in, const int* in_sizes, int n_in,
                              void* d_out, int out_size, void* d_ws,
                              size_t ws_size, hipStream_t stream) {
  const float* x = (const float*)d_in[0];
  const int* adj = (const int*)d_in[1];
  const float* W = (const float*)d_in[2];
  const float* a = (const float*)d_in[3];
  float* out = (float*)d_out;

  char* ws = (char*)d_ws;
  _Float16* Wh_t = (_Float16*)ws;                  // 1 MiB
  float* s1L = (float*)(ws + (1u << 20));          // 32 KiB
  float* s2L = s1L + N;                            // 32 KiB
  float* c0 = s2L + N;                             // 4 B
  _Float16* Bpack = (_Float16*)(ws + (2u << 20));  // 1 MiB
  float* accp = (float*)(ws + (4u << 20));         // JC*N*64*4 = 16 MiB
  float* lp = accp + (size_t)JC * N * OUT_DIM;     // 256 KiB

  wh_kernel<<<N, 64, 0, stream>>>(x, W, a, Wh_t, s1L, s2L);
  max_kernel<<<1, 256, 0, stream>>>(s1L, s2L, c0);
  bpack_kernel<<<N / 32, 256, 0, stream>>>(Wh_t, Bpack);
  attn_kernel<<<dim3(N / 64, JC), 256, 0, stream>>>(adj, Bpack, s1L, s2L, c0,
                                                    accp, lp);
  reduce_kernel<<<N * OUT_DIM / 256, 256, 0, stream>>>(accp, lp, out);
}